// Round 13
// baseline (179.371 us; speedup 1.0000x reference)
//
#include <hip/hip_runtime.h>
#include <math.h>

#define N_NODES 50000
#define N_EDGES 800000
#define NB1 196  // ceil(50000/256)

typedef __attribute__((ext_vector_type(8))) short bf16x8;
typedef __attribute__((ext_vector_type(4))) float f32x4;

// ---- bf16 helpers (manual RNE) ----
__device__ __forceinline__ unsigned short f2bf(float f) {
    unsigned u = __float_as_uint(f);
    unsigned r = (u + 0x7FFFu + ((u >> 16) & 1u)) >> 16;
    return (unsigned short)r;
}
__device__ __forceinline__ float bf2f(unsigned short u) {
    return __uint_as_float(((unsigned)u) << 16);
}
__device__ __forceinline__ unsigned pack2bf(float a, float b) {
    return (unsigned)f2bf(a) | ((unsigned)f2bf(b) << 16);
}

// Build ALL MFMA B-fragments (30 frags x 512 shorts) + zero degi.
__global__ __launch_bounds__(256) void kw_kernel(const float* __restrict__ We,
                                                 const float* __restrict__ Wa,
                                                 const float* __restrict__ Wn,
                                                 const float* __restrict__ W2,
                                                 short* __restrict__ Bpack,
                                                 int* __restrict__ degi) {
    int t = blockIdx.x * 256 + threadIdx.x;
    if (t < N_NODES) degi[t] = 0;
    if (t < 15360) {
        int f = t >> 9, u = t & 511, lane = u >> 3, j = u & 7;
        int c = lane & 15, G = lane >> 4;
        float v = 0.f;
        if (f < 4) {
            int s = f >> 1, n = f & 1;
            v = We[(16 * n + c) * 64 + 32 * s + 8 * G + j];
        } else if (f < 6) {
            int s = f - 4;
            if (c == 0) {
                int k = 32 * s + 8 * G + j;
                #pragma unroll
                for (int jj = 0; jj < 32; ++jj) v += Wa[64 + jj] * We[jj * 64 + k];
            }
        } else if (f < 22) {
            int qf = f - 6, s = qf >> 2, n = qf & 3;
            v = Wn[(16 * n + c) * 128 + 32 * s + 8 * G + j];
        } else {
            int qf = f - 22, s = qf >> 2, n = qf & 3;
            v = W2[(16 * n + c) * 96 + 32 * s + 8 * G + j];
        }
        Bpack[t] = (short)f2bf(v);
    }
}

// ---- FUSED: node pass (MFMA, blocks [0,782)) + hist (blocks [782,3907)) ----
__global__ __launch_bounds__(256) void node_hist_kernel(
    const float* __restrict__ h, const float* __restrict__ Wa,
    const short* __restrict__ Bpack, const int* __restrict__ dst,
    float* __restrict__ z, unsigned short* __restrict__ y16,
    float* __restrict__ asrc, float* __restrict__ adst,
    int* __restrict__ degi, int* __restrict__ ranks)
{
    __shared__ float zl[4][1088];    // per-wave 16x68 transpose buffer
    int t = threadIdx.x;
    if (blockIdx.x >= 782) {
        int e = (blockIdx.x - 782) * 256 + t;
        if (e < N_EDGES) ranks[e] = atomicAdd(&degi[dst[e]], 1);
        return;
    }
    int w = t >> 6, l = t & 63, c = l & 15, G = l >> 4;
    int T = blockIdx.x * 4 + w;
    if (T >= 3125) return;           // no barriers in this kernel -> safe
    int n0 = T * 16;
    const bf16x8* Bp = (const bf16x8*)Bpack;

    const float* hp = h + (size_t)(n0 + c) * 128 + 8 * G;
    bf16x8 a[4];
    #pragma unroll
    for (int s = 0; s < 4; ++s) {
        float4 lo = *(const float4*)(hp + 32 * s);
        float4 hi = *(const float4*)(hp + 32 * s + 4);
        a[s][0] = (short)f2bf(lo.x); a[s][1] = (short)f2bf(lo.y);
        a[s][2] = (short)f2bf(lo.z); a[s][3] = (short)f2bf(lo.w);
        a[s][4] = (short)f2bf(hi.x); a[s][5] = (short)f2bf(hi.y);
        a[s][6] = (short)f2bf(hi.z); a[s][7] = (short)f2bf(hi.w);
    }
    f32x4 acc[4] = {{0.f,0.f,0.f,0.f},{0.f,0.f,0.f,0.f},{0.f,0.f,0.f,0.f},{0.f,0.f,0.f,0.f}};
    #pragma unroll
    for (int n = 0; n < 4; ++n)
        #pragma unroll
        for (int s = 0; s < 4; ++s)
            acc[n] = __builtin_amdgcn_mfma_f32_16x16x32_bf16(a[s], Bp[(6 + 4*s + n)*64 + l], acc[n], 0, 0, 0);

    float was[4], wad[4];
    #pragma unroll
    for (int n = 0; n < 4; ++n) { was[n] = Wa[16*n + c]; wad[n] = Wa[96 + 16*n + c]; }

    #pragma unroll
    for (int r = 0; r < 4; ++r) {
        int row = n0 + 4 * G + r;
        #pragma unroll
        for (int n = 0; n < 4; ++n) {
            z[(size_t)row * 64 + 16 * n + c] = acc[n][r];
            zl[w][(4 * G + r) * 68 + 16 * n + c] = acc[n][r];
        }
        float ps = acc[0][r]*was[0] + acc[1][r]*was[1] + acc[2][r]*was[2] + acc[3][r]*was[3];
        float pd = acc[0][r]*wad[0] + acc[1][r]*wad[1] + acc[2][r]*wad[2] + acc[3][r]*wad[3];
        ps += __shfl_xor(ps, 1); ps += __shfl_xor(ps, 2);
        ps += __shfl_xor(ps, 4); ps += __shfl_xor(ps, 8);
        pd += __shfl_xor(pd, 1); pd += __shfl_xor(pd, 2);
        pd += __shfl_xor(pd, 4); pd += __shfl_xor(pd, 8);
        if (c == 0) { asrc[row] = ps; adst[row] = pd; }
    }

    bf16x8 ay[2];
    #pragma unroll
    for (int s = 0; s < 2; ++s)
        #pragma unroll
        for (int j = 0; j < 8; ++j)
            ay[s][j] = (short)f2bf(zl[w][c * 68 + 32 * s + 8 * G + j]);
    f32x4 accy[4] = {{0.f,0.f,0.f,0.f},{0.f,0.f,0.f,0.f},{0.f,0.f,0.f,0.f},{0.f,0.f,0.f,0.f}};
    #pragma unroll
    for (int n = 0; n < 4; ++n)
        #pragma unroll
        for (int s = 0; s < 2; ++s)
            accy[n] = __builtin_amdgcn_mfma_f32_16x16x32_bf16(ay[s], Bp[(22 + 4*s + n)*64 + l], accy[n], 0, 0, 0);
    #pragma unroll
    for (int r = 0; r < 4; ++r)
        #pragma unroll
        for (int n = 0; n < 4; ++n)
            y16[(size_t)(n0 + 4*G + r) * 64 + 16*n + c] = f2bf(accy[n][r]);
}

// ---- CSR scans ----
__global__ __launch_bounds__(256) void scan1_kernel(const int* __restrict__ degi,
                                                    int* __restrict__ partial) {
    int t = threadIdx.x, i = blockIdx.x * 256 + t;
    int d = (i < N_NODES) ? degi[i] : 0;
    #pragma unroll
    for (int off = 32; off; off >>= 1) d += __shfl_down(d, off);
    __shared__ int wsum[4];
    if ((t & 63) == 0) wsum[t >> 6] = d;
    __syncthreads();
    if (t == 0) partial[blockIdx.x] = wsum[0] + wsum[1] + wsum[2] + wsum[3];
}

__global__ __launch_bounds__(256) void scan2_kernel(int* __restrict__ partial) {
    __shared__ int s[256];
    int t = threadIdx.x;
    int v = (t < NB1) ? partial[t] : 0;
    s[t] = v; __syncthreads();
    for (int off = 1; off < 256; off <<= 1) {
        int x = (t >= off) ? s[t - off] : 0;
        __syncthreads();
        s[t] += x;
        __syncthreads();
    }
    if (t < NB1) partial[t] = s[t] - v;   // exclusive, in place
}

__global__ __launch_bounds__(256) void scan3_kernel(const int* __restrict__ degi,
                                                    const int* __restrict__ partial,
                                                    int* __restrict__ start) {
    __shared__ int s[256];
    int t = threadIdx.x, i = blockIdx.x * 256 + t;
    int d = (i < N_NODES) ? degi[i] : 0;
    s[t] = d; __syncthreads();
    for (int off = 1; off < 256; off <<= 1) {
        int x = (t >= off) ? s[t - off] : 0;
        __syncthreads();
        s[t] += x;
        __syncthreads();
    }
    if (i < N_NODES) start[i] = partial[blockIdx.x] + s[t] - d;
}

// ---- FUSED: edge pass (blocks [0,3125)) + scatter (blocks [3125,6250)) ----
__global__ __launch_bounds__(256, 2) void edge_scatter_kernel(
    const float* __restrict__ edge_feat, const int* __restrict__ src,
    const int* __restrict__ dst, const float* __restrict__ asrc,
    const float* __restrict__ adst, const short* __restrict__ Bpack,
    const int* __restrict__ ranks, const int* __restrict__ start,
    unsigned* __restrict__ gout, float* __restrict__ exarr,
    int2* __restrict__ edata)
{
    int t = threadIdx.x;
    if (blockIdx.x >= 3125) {
        int e = (blockIdx.x - 3125) * 256 + t;
        if (e < N_EDGES) edata[start[dst[e]] + ranks[e]] = make_int2(e, src[e]);
        return;
    }
    int w = t >> 6, l = t & 63;
    int c = l & 15, G = l >> 4;
    int wbase = blockIdx.x * 256 + w * 64;

    const bf16x8* Bp = (const bf16x8*)Bpack;
    bf16x8 b00 = Bp[0 * 64 + l];
    bf16x8 b01 = Bp[1 * 64 + l];
    bf16x8 b10 = Bp[2 * 64 + l];
    bf16x8 b11 = Bp[3 * 64 + l];
    bf16x8 b2a = Bp[4 * 64 + l];
    bf16x8 b2b = Bp[5 * 64 + l];

    int e = wbase + l;
    float apre = asrc[src[e]] + adst[dst[e]];
    float Ra[16];
    #pragma unroll
    for (int k = 0; k < 4; ++k)
        #pragma unroll
        for (int r = 0; r < 4; ++r)
            Ra[4 * k + r] = __shfl(apre, 16 * k + 4 * G + r);

    const float* efr = edge_feat + (size_t)(wbase + c) * 64 + G * 8;
    float4 n0 = *(const float4*)(efr);
    float4 n1 = *(const float4*)(efr + 4);
    float4 n2 = *(const float4*)(efr + 32);
    float4 n3 = *(const float4*)(efr + 36);

    #pragma unroll
    for (int k = 0; k < 4; ++k) {
        float4 c0 = n0, c1 = n1, c2 = n2, c3 = n3;
        if (k < 3) {
            const float* efn = edge_feat + (size_t)(wbase + 16 * (k + 1) + c) * 64 + G * 8;
            n0 = *(const float4*)(efn);
            n1 = *(const float4*)(efn + 4);
            n2 = *(const float4*)(efn + 32);
            n3 = *(const float4*)(efn + 36);
        }
        bf16x8 a0, a1;
        a0[0] = (short)f2bf(c0.x); a0[1] = (short)f2bf(c0.y);
        a0[2] = (short)f2bf(c0.z); a0[3] = (short)f2bf(c0.w);
        a0[4] = (short)f2bf(c1.x); a0[5] = (short)f2bf(c1.y);
        a0[6] = (short)f2bf(c1.z); a0[7] = (short)f2bf(c1.w);
        a1[0] = (short)f2bf(c2.x); a1[1] = (short)f2bf(c2.y);
        a1[2] = (short)f2bf(c2.z); a1[3] = (short)f2bf(c2.w);
        a1[4] = (short)f2bf(c3.x); a1[5] = (short)f2bf(c3.y);
        a1[6] = (short)f2bf(c3.z); a1[7] = (short)f2bf(c3.w);

        f32x4 acc0 = {0.f, 0.f, 0.f, 0.f};
        f32x4 acc1 = {0.f, 0.f, 0.f, 0.f};
        f32x4 acc2 = {0.f, 0.f, 0.f, 0.f};
        acc0 = __builtin_amdgcn_mfma_f32_16x16x32_bf16(a0, b00, acc0, 0, 0, 0);
        acc0 = __builtin_amdgcn_mfma_f32_16x16x32_bf16(a1, b10, acc0, 0, 0, 0);
        acc1 = __builtin_amdgcn_mfma_f32_16x16x32_bf16(a0, b01, acc1, 0, 0, 0);
        acc1 = __builtin_amdgcn_mfma_f32_16x16x32_bf16(a1, b11, acc1, 0, 0, 0);
        acc2 = __builtin_amdgcn_mfma_f32_16x16x32_bf16(a0, b2a, acc2, 0, 0, 0);
        acc2 = __builtin_amdgcn_mfma_f32_16x16x32_bf16(a1, b2b, acc2, 0, 0, 0);

        #pragma unroll
        for (int r = 0; r < 4; ++r) {
            int eo = wbase + 16 * k + 4 * G + r;
            gout[(size_t)eo * 16 + c] = pack2bf(acc0[r], acc1[r]);
            if (c == 0) {
                float aa = Ra[4 * k + r] + acc2[r];
                float sg = aa > 0.f ? aa : 0.01f * aa;
                exarr[eo] = __expf(sg);   // segmax shift mathematically redundant
            }
        }
    }
}

// ---- Pass B: per-node walk; edata+ex preloaded per 64-window; inner loop has
//      ZERO dependent-load levels ----
__global__ __launch_bounds__(256) void agg_kernel(
    const unsigned* __restrict__ gout, const float* __restrict__ exarr,
    const int2* __restrict__ edata, const ushort4* __restrict__ y16v,
    const int* __restrict__ start, const int* __restrict__ degi,
    const float* __restrict__ z, const float* __restrict__ W2,
    float* __restrict__ out)
{
    __shared__ float stu[4][164];    // [64:128)=uy, [128:160)=v32
    __shared__ float sW2b[64 * 36];
    int t = threadIdx.x, w = t >> 6, l = t & 63, g = l >> 4, q = l & 15;
    for (int idx = t; idx < 64 * 32; idx += 256)
        sW2b[(idx >> 5) * 36 + (idx & 31)] = W2[(idx >> 5) * 96 + 64 + (idx & 31)];
    __syncthreads();

    int d    = blockIdx.x * 4 + w;           // grid exact: 12500*4 = 50000
    int base = __builtin_amdgcn_readfirstlane(start[d]);
    int deg  = __builtin_amdgcn_readfirstlane(degi[d]);
    float2 tg = make_float2(0.f, 0.f);
    float4 uy4 = make_float4(0.f, 0.f, 0.f, 0.f);
    float den = 0.f;

    for (int c0 = 0; c0 < deg; c0 += 64) {
        int cc = min(deg - c0, 64);          // wave-uniform
        int meid = 0, msrc = 0; float mex = 0.f;
        if (l < cc) {
            int2 md = edata[base + c0 + l];
            meid = md.x; msrc = md.y;
            mex = exarr[md.x];               // L2-resident gather, once per edge
        }
        for (int cI = 0; cI < cc; cI += 16) {
            int e0, e1, e2, e3, s0, s1, s2, s3;
            float x0, x1, x2, x3;
            #define PREP(P, EP, SP, XP)                                      \
                { int sl = cI + 4 * P + g; bool vv = sl < cc;               \
                  int slc = vv ? sl : 0;                                     \
                  EP = __shfl(meid, slc); SP = __shfl(msrc, slc);            \
                  float xx = __shfl(mex, slc); XP = vv ? xx : 0.f; }
            PREP(0, e0, s0, x0) PREP(1, e1, s1, x1)
            PREP(2, e2, s2, x2) PREP(3, e3, s3, x3)
            #undef PREP
            unsigned ga0 = gout[(size_t)e0 * 16 + q];
            unsigned ga1 = gout[(size_t)e1 * 16 + q];
            unsigned ga2 = gout[(size_t)e2 * 16 + q];
            unsigned ga3 = gout[(size_t)e3 * 16 + q];
            ushort4 ya0 = y16v[(size_t)s0 * 16 + q];
            ushort4 ya1 = y16v[(size_t)s1 * 16 + q];
            ushort4 ya2 = y16v[(size_t)s2 * 16 + q];
            ushort4 ya3 = y16v[(size_t)s3 * 16 + q];
            #define ACCP(XP, GA, YA)                                         \
                { tg.x += XP * bf2f((unsigned short)(GA & 0xffffu));         \
                  tg.y += XP * bf2f((unsigned short)(GA >> 16));             \
                  uy4.x += XP * bf2f(YA.x); uy4.y += XP * bf2f(YA.y);        \
                  uy4.z += XP * bf2f(YA.z); uy4.w += XP * bf2f(YA.w);        \
                  den += XP; }
            ACCP(x0, ga0, ya0) ACCP(x1, ga1, ya1)
            ACCP(x2, ga2, ya2) ACCP(x3, ga3, ya3)
            #undef ACCP
        }
    }

    // combine the 4 edge-slot groups
    tg.x += __shfl_xor(tg.x, 16); tg.x += __shfl_xor(tg.x, 32);
    tg.y += __shfl_xor(tg.y, 16); tg.y += __shfl_xor(tg.y, 32);
    uy4.x += __shfl_xor(uy4.x, 16); uy4.x += __shfl_xor(uy4.x, 32);
    uy4.y += __shfl_xor(uy4.y, 16); uy4.y += __shfl_xor(uy4.y, 32);
    uy4.z += __shfl_xor(uy4.z, 16); uy4.z += __shfl_xor(uy4.z, 32);
    uy4.w += __shfl_xor(uy4.w, 16); uy4.w += __shfl_xor(uy4.w, 32);
    den += __shfl_xor(den, 16); den += __shfl_xor(den, 32);

    if (l < 16) {
        *(float4*)&stu[w][64 + q * 4] = uy4;
        stu[w][128 + q] = tg.x;        // v32[j=q]
        stu[w][144 + q] = tg.y;        // v32[j=16+q]
    }
    // same wave writes+reads stu[w] -> in-order, no barrier needed

    if (deg > 0) {
        float r = 0.f;
        #pragma unroll
        for (int k = 0; k < 8; ++k) {
            float4 wv = *(const float4*)&sW2b[l * 36 + k * 4];
            float4 vv = *(const float4*)&stu[w][128 + k * 4];
            r += wv.x * vv.x + wv.y * vv.y + wv.z * vv.z + wv.w * vv.w;
        }
        out[(size_t)d * 64 + l] = (r + stu[w][64 + l]) / den;
    } else {
        out[(size_t)d * 64 + l] = z[(size_t)d * 64 + l];
    }
}

extern "C" void kernel_launch(void* const* d_in, const int* in_sizes, int n_in,
                              void* d_out, int out_size, void* d_ws, size_t ws_size,
                              hipStream_t stream) {
    const float* h         = (const float*)d_in[0];
    const float* edge_feat = (const float*)d_in[1];
    const int*   src       = (const int*)d_in[2];
    const int*   dst       = (const int*)d_in[3];
    const float* Wn        = (const float*)d_in[4];
    const float* We        = (const float*)d_in[5];
    const float* Wa        = (const float*)d_in[6];
    const float* W2        = (const float*)d_in[7];
    float* out = (float*)d_out;

    char* p = (char*)d_ws;
    unsigned*       gout   = (unsigned*)p;       p += (size_t)N_EDGES * 16 * 4;   // 51.2 MB
    float*          z      = (float*)p;          p += (size_t)N_NODES * 64 * 4;   // 12.8 MB
    unsigned short* y16    = (unsigned short*)p; p += (size_t)N_NODES * 64 * 2;   // 6.4 MB
    int2*           edata  = (int2*)p;           p += (size_t)N_EDGES * 8;        // 6.4 MB
    float*          exarr  = (float*)p;          p += (size_t)N_EDGES * 4;        // 3.2 MB
    float*          asrc   = (float*)p;          p += (size_t)N_NODES * 4;
    float*          adst   = (float*)p;          p += (size_t)N_NODES * 4;
    int*            degi   = (int*)p;            p += (size_t)N_NODES * 4;
    int*            start  = (int*)p;            p += (size_t)N_NODES * 4;
    int*            ranks  = (int*)p;            p += (size_t)N_EDGES * 4;        // 3.2 MB
    int*            partial= (int*)p;            p += (size_t)256 * 4;
    short*          Bpack  = (short*)p;          p += (size_t)15360 * 2;          // 30 KB

    kw_kernel<<<NB1, 256, 0, stream>>>(We, Wa, Wn, W2, Bpack, degi);
    node_hist_kernel<<<782 + 3125, 256, 0, stream>>>(h, Wa, Bpack, dst, z, y16,
                                                     asrc, adst, degi, ranks);
    scan1_kernel<<<NB1, 256, 0, stream>>>(degi, partial);
    scan2_kernel<<<1, 256, 0, stream>>>(partial);
    scan3_kernel<<<NB1, 256, 0, stream>>>(degi, partial, start);
    edge_scatter_kernel<<<3125 + 3125, 256, 0, stream>>>(edge_feat, src, dst, asrc, adst,
                                                         Bpack, ranks, start,
                                                         gout, exarr, edata);
    agg_kernel<<<N_NODES / 4, 256, 0, stream>>>(gout, exarr, edata, (const ushort4*)y16,
                                                start, degi, z, W2, out);
}

// Round 14
// 177.100 us; speedup vs baseline: 1.0128x; 1.0128x over previous
//
#include <hip/hip_runtime.h>
#include <math.h>

#define N_NODES 50000
#define N_EDGES 800000
#define NB1 196  // ceil(50000/256)

typedef __attribute__((ext_vector_type(8))) short bf16x8;
typedef __attribute__((ext_vector_type(4))) float f32x4;

// ---- bf16 helpers (manual RNE) ----
__device__ __forceinline__ unsigned short f2bf(float f) {
    unsigned u = __float_as_uint(f);
    unsigned r = (u + 0x7FFFu + ((u >> 16) & 1u)) >> 16;
    return (unsigned short)r;
}
__device__ __forceinline__ float bf2f(unsigned short u) {
    return __uint_as_float(((unsigned)u) << 16);
}
__device__ __forceinline__ unsigned pack2bf(float a, float b) {
    return (unsigned)f2bf(a) | ((unsigned)f2bf(b) << 16);
}

// Build ALL MFMA B-fragments (30 frags x 512 shorts) + zero degi.
__global__ __launch_bounds__(256) void kw_kernel(const float* __restrict__ We,
                                                 const float* __restrict__ Wa,
                                                 const float* __restrict__ Wn,
                                                 const float* __restrict__ W2,
                                                 short* __restrict__ Bpack,
                                                 int* __restrict__ degi) {
    int t = blockIdx.x * 256 + threadIdx.x;
    if (t < N_NODES) degi[t] = 0;
    if (t < 15360) {
        int f = t >> 9, u = t & 511, lane = u >> 3, j = u & 7;
        int c = lane & 15, G = lane >> 4;
        float v = 0.f;
        if (f < 4) {
            int s = f >> 1, n = f & 1;
            v = We[(16 * n + c) * 64 + 32 * s + 8 * G + j];
        } else if (f < 6) {
            int s = f - 4;
            if (c == 0) {
                int k = 32 * s + 8 * G + j;
                #pragma unroll
                for (int jj = 0; jj < 32; ++jj) v += Wa[64 + jj] * We[jj * 64 + k];
            }
        } else if (f < 22) {
            int qf = f - 6, s = qf >> 2, n = qf & 3;
            v = Wn[(16 * n + c) * 128 + 32 * s + 8 * G + j];
        } else {
            int qf = f - 22, s = qf >> 2, n = qf & 3;
            v = W2[(16 * n + c) * 96 + 32 * s + 8 * G + j];
        }
        Bpack[t] = (short)f2bf(v);
    }
}

// ---- FUSED: node pass (MFMA, blocks [0,782)) + hist (blocks [782,3907)) ----
__global__ __launch_bounds__(256) void node_hist_kernel(
    const float* __restrict__ h, const float* __restrict__ Wa,
    const short* __restrict__ Bpack, const int* __restrict__ dst,
    float* __restrict__ z, unsigned short* __restrict__ y16,
    float* __restrict__ asrc, float* __restrict__ adst,
    int* __restrict__ degi, int* __restrict__ ranks)
{
    __shared__ float zl[4][1088];    // per-wave 16x68 transpose buffer
    int t = threadIdx.x;
    if (blockIdx.x >= 782) {
        int e = (blockIdx.x - 782) * 256 + t;
        if (e < N_EDGES) ranks[e] = atomicAdd(&degi[dst[e]], 1);
        return;
    }
    int w = t >> 6, l = t & 63, c = l & 15, G = l >> 4;
    int T = blockIdx.x * 4 + w;
    if (T >= 3125) return;           // no barriers in this kernel -> safe
    int n0 = T * 16;
    const bf16x8* Bp = (const bf16x8*)Bpack;

    const float* hp = h + (size_t)(n0 + c) * 128 + 8 * G;
    bf16x8 a[4];
    #pragma unroll
    for (int s = 0; s < 4; ++s) {
        float4 lo = *(const float4*)(hp + 32 * s);
        float4 hi = *(const float4*)(hp + 32 * s + 4);
        a[s][0] = (short)f2bf(lo.x); a[s][1] = (short)f2bf(lo.y);
        a[s][2] = (short)f2bf(lo.z); a[s][3] = (short)f2bf(lo.w);
        a[s][4] = (short)f2bf(hi.x); a[s][5] = (short)f2bf(hi.y);
        a[s][6] = (short)f2bf(hi.z); a[s][7] = (short)f2bf(hi.w);
    }
    f32x4 acc[4] = {{0.f,0.f,0.f,0.f},{0.f,0.f,0.f,0.f},{0.f,0.f,0.f,0.f},{0.f,0.f,0.f,0.f}};
    #pragma unroll
    for (int n = 0; n < 4; ++n)
        #pragma unroll
        for (int s = 0; s < 4; ++s)
            acc[n] = __builtin_amdgcn_mfma_f32_16x16x32_bf16(a[s], Bp[(6 + 4*s + n)*64 + l], acc[n], 0, 0, 0);

    float was[4], wad[4];
    #pragma unroll
    for (int n = 0; n < 4; ++n) { was[n] = Wa[16*n + c]; wad[n] = Wa[96 + 16*n + c]; }

    #pragma unroll
    for (int r = 0; r < 4; ++r) {
        int row = n0 + 4 * G + r;
        #pragma unroll
        for (int n = 0; n < 4; ++n) {
            z[(size_t)row * 64 + 16 * n + c] = acc[n][r];
            zl[w][(4 * G + r) * 68 + 16 * n + c] = acc[n][r];
        }
        float ps = acc[0][r]*was[0] + acc[1][r]*was[1] + acc[2][r]*was[2] + acc[3][r]*was[3];
        float pd = acc[0][r]*wad[0] + acc[1][r]*wad[1] + acc[2][r]*wad[2] + acc[3][r]*wad[3];
        ps += __shfl_xor(ps, 1); ps += __shfl_xor(ps, 2);
        ps += __shfl_xor(ps, 4); ps += __shfl_xor(ps, 8);
        pd += __shfl_xor(pd, 1); pd += __shfl_xor(pd, 2);
        pd += __shfl_xor(pd, 4); pd += __shfl_xor(pd, 8);
        if (c == 0) { asrc[row] = ps; adst[row] = pd; }
    }

    bf16x8 ay[2];
    #pragma unroll
    for (int s = 0; s < 2; ++s)
        #pragma unroll
        for (int j = 0; j < 8; ++j)
            ay[s][j] = (short)f2bf(zl[w][c * 68 + 32 * s + 8 * G + j]);
    f32x4 accy[4] = {{0.f,0.f,0.f,0.f},{0.f,0.f,0.f,0.f},{0.f,0.f,0.f,0.f},{0.f,0.f,0.f,0.f}};
    #pragma unroll
    for (int n = 0; n < 4; ++n)
        #pragma unroll
        for (int s = 0; s < 2; ++s)
            accy[n] = __builtin_amdgcn_mfma_f32_16x16x32_bf16(ay[s], Bp[(22 + 4*s + n)*64 + l], accy[n], 0, 0, 0);
    #pragma unroll
    for (int r = 0; r < 4; ++r)
        #pragma unroll
        for (int n = 0; n < 4; ++n)
            y16[(size_t)(n0 + 4*G + r) * 64 + 16*n + c] = f2bf(accy[n][r]);
}

// ---- CSR scans ----
__global__ __launch_bounds__(256) void scan1_kernel(const int* __restrict__ degi,
                                                    int* __restrict__ partial) {
    int t = threadIdx.x, i = blockIdx.x * 256 + t;
    int d = (i < N_NODES) ? degi[i] : 0;
    #pragma unroll
    for (int off = 32; off; off >>= 1) d += __shfl_down(d, off);
    __shared__ int wsum[4];
    if ((t & 63) == 0) wsum[t >> 6] = d;
    __syncthreads();
    if (t == 0) partial[blockIdx.x] = wsum[0] + wsum[1] + wsum[2] + wsum[3];
}

__global__ __launch_bounds__(256) void scan2_kernel(int* __restrict__ partial) {
    __shared__ int s[256];
    int t = threadIdx.x;
    int v = (t < NB1) ? partial[t] : 0;
    s[t] = v; __syncthreads();
    for (int off = 1; off < 256; off <<= 1) {
        int x = (t >= off) ? s[t - off] : 0;
        __syncthreads();
        s[t] += x;
        __syncthreads();
    }
    if (t < NB1) partial[t] = s[t] - v;   // exclusive, in place
}

__global__ __launch_bounds__(256) void scan3_kernel(const int* __restrict__ degi,
                                                    const int* __restrict__ partial,
                                                    int* __restrict__ start) {
    __shared__ int s[256];
    int t = threadIdx.x, i = blockIdx.x * 256 + t;
    int d = (i < N_NODES) ? degi[i] : 0;
    s[t] = d; __syncthreads();
    for (int off = 1; off < 256; off <<= 1) {
        int x = (t >= off) ? s[t - off] : 0;
        __syncthreads();
        s[t] += x;
        __syncthreads();
    }
    if (i < N_NODES) start[i] = partial[blockIdx.x] + s[t] - d;
}

// ---- FUSED: edge pass (blocks [0,3125)) + scatter (blocks [3125,6250)) ----
__global__ __launch_bounds__(256, 2) void edge_scatter_kernel(
    const float* __restrict__ edge_feat, const int* __restrict__ src,
    const int* __restrict__ dst, const float* __restrict__ asrc,
    const float* __restrict__ adst, const short* __restrict__ Bpack,
    const int* __restrict__ ranks, const int* __restrict__ start,
    unsigned* __restrict__ gout, float* __restrict__ exarr,
    int2* __restrict__ edata)
{
    int t = threadIdx.x;
    if (blockIdx.x >= 3125) {
        int e = (blockIdx.x - 3125) * 256 + t;
        if (e < N_EDGES) edata[start[dst[e]] + ranks[e]] = make_int2(e, src[e]);
        return;
    }
    int w = t >> 6, l = t & 63;
    int c = l & 15, G = l >> 4;
    int wbase = blockIdx.x * 256 + w * 64;

    const bf16x8* Bp = (const bf16x8*)Bpack;
    bf16x8 b00 = Bp[0 * 64 + l];
    bf16x8 b01 = Bp[1 * 64 + l];
    bf16x8 b10 = Bp[2 * 64 + l];
    bf16x8 b11 = Bp[3 * 64 + l];
    bf16x8 b2a = Bp[4 * 64 + l];
    bf16x8 b2b = Bp[5 * 64 + l];

    int e = wbase + l;
    float apre = asrc[src[e]] + adst[dst[e]];
    float Ra[16];
    #pragma unroll
    for (int k = 0; k < 4; ++k)
        #pragma unroll
        for (int r = 0; r < 4; ++r)
            Ra[4 * k + r] = __shfl(apre, 16 * k + 4 * G + r);

    const float* efr = edge_feat + (size_t)(wbase + c) * 64 + G * 8;
    float4 n0 = *(const float4*)(efr);
    float4 n1 = *(const float4*)(efr + 4);
    float4 n2 = *(const float4*)(efr + 32);
    float4 n3 = *(const float4*)(efr + 36);

    #pragma unroll
    for (int k = 0; k < 4; ++k) {
        float4 c0 = n0, c1 = n1, c2 = n2, c3 = n3;
        if (k < 3) {
            const float* efn = edge_feat + (size_t)(wbase + 16 * (k + 1) + c) * 64 + G * 8;
            n0 = *(const float4*)(efn);
            n1 = *(const float4*)(efn + 4);
            n2 = *(const float4*)(efn + 32);
            n3 = *(const float4*)(efn + 36);
        }
        bf16x8 a0, a1;
        a0[0] = (short)f2bf(c0.x); a0[1] = (short)f2bf(c0.y);
        a0[2] = (short)f2bf(c0.z); a0[3] = (short)f2bf(c0.w);
        a0[4] = (short)f2bf(c1.x); a0[5] = (short)f2bf(c1.y);
        a0[6] = (short)f2bf(c1.z); a0[7] = (short)f2bf(c1.w);
        a1[0] = (short)f2bf(c2.x); a1[1] = (short)f2bf(c2.y);
        a1[2] = (short)f2bf(c2.z); a1[3] = (short)f2bf(c2.w);
        a1[4] = (short)f2bf(c3.x); a1[5] = (short)f2bf(c3.y);
        a1[6] = (short)f2bf(c3.z); a1[7] = (short)f2bf(c3.w);

        f32x4 acc0 = {0.f, 0.f, 0.f, 0.f};
        f32x4 acc1 = {0.f, 0.f, 0.f, 0.f};
        f32x4 acc2 = {0.f, 0.f, 0.f, 0.f};
        acc0 = __builtin_amdgcn_mfma_f32_16x16x32_bf16(a0, b00, acc0, 0, 0, 0);
        acc0 = __builtin_amdgcn_mfma_f32_16x16x32_bf16(a1, b10, acc0, 0, 0, 0);
        acc1 = __builtin_amdgcn_mfma_f32_16x16x32_bf16(a0, b01, acc1, 0, 0, 0);
        acc1 = __builtin_amdgcn_mfma_f32_16x16x32_bf16(a1, b11, acc1, 0, 0, 0);
        acc2 = __builtin_amdgcn_mfma_f32_16x16x32_bf16(a0, b2a, acc2, 0, 0, 0);
        acc2 = __builtin_amdgcn_mfma_f32_16x16x32_bf16(a1, b2b, acc2, 0, 0, 0);

        #pragma unroll
        for (int r = 0; r < 4; ++r) {
            int eo = wbase + 16 * k + 4 * G + r;
            gout[(size_t)eo * 16 + c] = pack2bf(acc0[r], acc1[r]);
            if (c == 0) {
                float aa = Ra[4 * k + r] + acc2[r];
                float sg = aa > 0.f ? aa : 0.01f * aa;
                exarr[eo] = __expf(sg);   // segmax shift mathematically redundant
            }
        }
    }
}

// ---- Pass B: per-node walk; edata+ex preloaded per 64-window; inner loop has
//      ZERO dependent-load levels ----
__global__ __launch_bounds__(256) void agg_kernel(
    const unsigned* __restrict__ gout, const float* __restrict__ exarr,
    const int2* __restrict__ edata, const ushort4* __restrict__ y16v,
    const int* __restrict__ start, const int* __restrict__ degi,
    const float* __restrict__ z, const float* __restrict__ W2,
    float* __restrict__ out)
{
    __shared__ float stu[4][164];    // [64:128)=uy, [128:160)=v32
    __shared__ float sW2b[64 * 36];
    int t = threadIdx.x, w = t >> 6, l = t & 63, g = l >> 4, q = l & 15;
    for (int idx = t; idx < 64 * 32; idx += 256)
        sW2b[(idx >> 5) * 36 + (idx & 31)] = W2[(idx >> 5) * 96 + 64 + (idx & 31)];
    __syncthreads();

    int d    = blockIdx.x * 4 + w;           // grid exact: 12500*4 = 50000
    int base = __builtin_amdgcn_readfirstlane(start[d]);
    int deg  = __builtin_amdgcn_readfirstlane(degi[d]);
    float2 tg = make_float2(0.f, 0.f);
    float4 uy4 = make_float4(0.f, 0.f, 0.f, 0.f);
    float den = 0.f;

    for (int c0 = 0; c0 < deg; c0 += 64) {
        int cc = min(deg - c0, 64);          // wave-uniform
        int meid = 0, msrc = 0; float mex = 0.f;
        if (l < cc) {
            int2 md = edata[base + c0 + l];
            meid = md.x; msrc = md.y;
            mex = exarr[md.x];               // L2-resident gather, once per edge
        }
        for (int cI = 0; cI < cc; cI += 16) {
            int e0, e1, e2, e3, s0, s1, s2, s3;
            float x0, x1, x2, x3;
            #define PREP(P, EP, SP, XP)                                      \
                { int sl = cI + 4 * P + g; bool vv = sl < cc;               \
                  int slc = vv ? sl : 0;                                     \
                  EP = __shfl(meid, slc); SP = __shfl(msrc, slc);            \
                  float xx = __shfl(mex, slc); XP = vv ? xx : 0.f; }
            PREP(0, e0, s0, x0) PREP(1, e1, s1, x1)
            PREP(2, e2, s2, x2) PREP(3, e3, s3, x3)
            #undef PREP
            unsigned ga0 = gout[(size_t)e0 * 16 + q];
            unsigned ga1 = gout[(size_t)e1 * 16 + q];
            unsigned ga2 = gout[(size_t)e2 * 16 + q];
            unsigned ga3 = gout[(size_t)e3 * 16 + q];
            ushort4 ya0 = y16v[(size_t)s0 * 16 + q];
            ushort4 ya1 = y16v[(size_t)s1 * 16 + q];
            ushort4 ya2 = y16v[(size_t)s2 * 16 + q];
            ushort4 ya3 = y16v[(size_t)s3 * 16 + q];
            #define ACCP(XP, GA, YA)                                         \
                { tg.x += XP * bf2f((unsigned short)(GA & 0xffffu));         \
                  tg.y += XP * bf2f((unsigned short)(GA >> 16));             \
                  uy4.x += XP * bf2f(YA.x); uy4.y += XP * bf2f(YA.y);        \
                  uy4.z += XP * bf2f(YA.z); uy4.w += XP * bf2f(YA.w);        \
                  den += XP; }
            ACCP(x0, ga0, ya0) ACCP(x1, ga1, ya1)
            ACCP(x2, ga2, ya2) ACCP(x3, ga3, ya3)
            #undef ACCP
        }
    }

    // combine the 4 edge-slot groups
    tg.x += __shfl_xor(tg.x, 16); tg.x += __shfl_xor(tg.x, 32);
    tg.y += __shfl_xor(tg.y, 16); tg.y += __shfl_xor(tg.y, 32);
    uy4.x += __shfl_xor(uy4.x, 16); uy4.x += __shfl_xor(uy4.x, 32);
    uy4.y += __shfl_xor(uy4.y, 16); uy4.y += __shfl_xor(uy4.y, 32);
    uy4.z += __shfl_xor(uy4.z, 16); uy4.z += __shfl_xor(uy4.z, 32);
    uy4.w += __shfl_xor(uy4.w, 16); uy4.w += __shfl_xor(uy4.w, 32);
    den += __shfl_xor(den, 16); den += __shfl_xor(den, 32);

    if (l < 16) {
        *(float4*)&stu[w][64 + q * 4] = uy4;
        stu[w][128 + q] = tg.x;        // v32[j=q]
        stu[w][144 + q] = tg.y;        // v32[j=16+q]
    }
    // same wave writes+reads stu[w] -> in-order, no barrier needed

    if (deg > 0) {
        float r = 0.f;
        #pragma unroll
        for (int k = 0; k < 8; ++k) {
            float4 wv = *(const float4*)&sW2b[l * 36 + k * 4];
            float4 vv = *(const float4*)&stu[w][128 + k * 4];
            r += wv.x * vv.x + wv.y * vv.y + wv.z * vv.z + wv.w * vv.w;
        }
        out[(size_t)d * 64 + l] = (r + stu[w][64 + l]) / den;
    } else {
        out[(size_t)d * 64 + l] = z[(size_t)d * 64 + l];
    }
}

extern "C" void kernel_launch(void* const* d_in, const int* in_sizes, int n_in,
                              void* d_out, int out_size, void* d_ws, size_t ws_size,
                              hipStream_t stream) {
    const float* h         = (const float*)d_in[0];
    const float* edge_feat = (const float*)d_in[1];
    const int*   src       = (const int*)d_in[2];
    const int*   dst       = (const int*)d_in[3];
    const float* Wn        = (const float*)d_in[4];
    const float* We        = (const float*)d_in[5];
    const float* Wa        = (const float*)d_in[6];
    const float* W2        = (const float*)d_in[7];
    float* out = (float*)d_out;

    char* p = (char*)d_ws;
    unsigned*       gout   = (unsigned*)p;       p += (size_t)N_EDGES * 16 * 4;   // 51.2 MB
    float*          z      = (float*)p;          p += (size_t)N_NODES * 64 * 4;   // 12.8 MB
    unsigned short* y16    = (unsigned short*)p; p += (size_t)N_NODES * 64 * 2;   // 6.4 MB
    int2*           edata  = (int2*)p;           p += (size_t)N_EDGES * 8;        // 6.4 MB
    float*          exarr  = (float*)p;          p += (size_t)N_EDGES * 4;        // 3.2 MB
    float*          asrc   = (float*)p;          p += (size_t)N_NODES * 4;
    float*          adst   = (float*)p;          p += (size_t)N_NODES * 4;
    int*            degi   = (int*)p;            p += (size_t)N_NODES * 4;
    int*            start  = (int*)p;            p += (size_t)N_NODES * 4;
    int*            ranks  = (int*)p;            p += (size_t)N_EDGES * 4;        // 3.2 MB
    int*            partial= (int*)p;            p += (size_t)256 * 4;
    short*          Bpack  = (short*)p;          p += (size_t)15360 * 2;          // 30 KB

    kw_kernel<<<NB1, 256, 0, stream>>>(We, Wa, Wn, W2, Bpack, degi);
    node_hist_kernel<<<782 + 3125, 256, 0, stream>>>(h, Wa, Bpack, dst, z, y16,
                                                     asrc, adst, degi, ranks);
    scan1_kernel<<<NB1, 256, 0, stream>>>(degi, partial);
    scan2_kernel<<<1, 256, 0, stream>>>(partial);
    scan3_kernel<<<NB1, 256, 0, stream>>>(degi, partial, start);
    edge_scatter_kernel<<<3125 + 3125, 256, 0, stream>>>(edge_feat, src, dst, asrc, adst,
                                                         Bpack, ranks, start,
                                                         gout, exarr, edata);
    agg_kernel<<<N_NODES / 4, 256, 0, stream>>>(gout, exarr, edata, (const ushort4*)y16,
                                                start, degi, z, W2, out);
}

// Round 15
// 169.207 us; speedup vs baseline: 1.0601x; 1.0466x over previous
//
#include <hip/hip_runtime.h>
#include <math.h>

#define N_NODES 50000
#define N_EDGES 800000
#define NB1 196  // ceil(50000/256)

typedef __attribute__((ext_vector_type(8))) short bf16x8;
typedef __attribute__((ext_vector_type(4))) float f32x4;

// ---- bf16 helpers (manual RNE) ----
__device__ __forceinline__ unsigned short f2bf(float f) {
    unsigned u = __float_as_uint(f);
    unsigned r = (u + 0x7FFFu + ((u >> 16) & 1u)) >> 16;
    return (unsigned short)r;
}
__device__ __forceinline__ float bf2f(unsigned short u) {
    return __uint_as_float(((unsigned)u) << 16);
}
__device__ __forceinline__ unsigned pack2bf(float a, float b) {
    return (unsigned)f2bf(a) | ((unsigned)f2bf(b) << 16);
}

// Build ALL MFMA B-fragments (34 frags x 512 shorts) + zero degi.
// Frag f, element u=lane*8+j, c=lane&15, G=lane>>4, k'=32s+8G+j:
//  f 0-7  : Wc^T, s=f>>2, n=f&3 : Wc[16n+c][k'] = sum_kk W2[(16n+c)*96+64+kk]*We[kk*64+k']
//  f 8-9  : wca col0, s=f-8 : c==0 ? sum_jj Wa[64+jj]*We[jj*64+k'] : 0
//  f 10-25: Wn^T  (node z), qf=f-10, s=qf>>2, n=qf&3 : Wn[(16n+c)*128 + k']
//  f 26-33: W2a^T (node y), qf=f-26, s=qf>>2, n=qf&3 : W2[(16n+c)*96 + k']
__global__ __launch_bounds__(256) void kw_kernel(const float* __restrict__ We,
                                                 const float* __restrict__ Wa,
                                                 const float* __restrict__ Wn,
                                                 const float* __restrict__ W2,
                                                 short* __restrict__ Bpack,
                                                 int* __restrict__ degi) {
    int t = blockIdx.x * 256 + threadIdx.x;
    if (t < N_NODES) degi[t] = 0;
    if (t < 34 * 512) {
        int f = t >> 9, u = t & 511, lane = u >> 3, j = u & 7;
        int c = lane & 15, G = lane >> 4;
        float v = 0.f;
        if (f < 8) {
            int s = f >> 2, n = f & 3;
            int kp = 32 * s + 8 * G + j;
            #pragma unroll
            for (int kk = 0; kk < 32; ++kk)
                v += W2[(16 * n + c) * 96 + 64 + kk] * We[kk * 64 + kp];
        } else if (f < 10) {
            int s = f - 8;
            if (c == 0) {
                int kp = 32 * s + 8 * G + j;
                #pragma unroll
                for (int jj = 0; jj < 32; ++jj) v += Wa[64 + jj] * We[jj * 64 + kp];
            }
        } else if (f < 26) {
            int qf = f - 10, s = qf >> 2, n = qf & 3;
            v = Wn[(16 * n + c) * 128 + 32 * s + 8 * G + j];
        } else {
            int qf = f - 26, s = qf >> 2, n = qf & 3;
            v = W2[(16 * n + c) * 96 + 32 * s + 8 * G + j];
        }
        Bpack[t] = (short)f2bf(v);
    }
}

// ---- FUSED: node pass (MFMA, blocks [0,782)) + hist (blocks [782,3907)) ----
// y16p layout: ushort4 at [row*16 + c] = { y[c], y[16+c], y[32+c], y[48+c] }
__global__ __launch_bounds__(256) void node_hist_kernel(
    const float* __restrict__ h, const float* __restrict__ Wa,
    const short* __restrict__ Bpack, const int* __restrict__ dst,
    float* __restrict__ z, ushort4* __restrict__ y16p,
    float* __restrict__ asrc, float* __restrict__ adst,
    int* __restrict__ degi, int* __restrict__ ranks)
{
    __shared__ float zl[4][1088];    // per-wave 16x68 transpose buffer
    int t = threadIdx.x;
    if (blockIdx.x >= 782) {
        int e = (blockIdx.x - 782) * 256 + t;
        if (e < N_EDGES) ranks[e] = atomicAdd(&degi[dst[e]], 1);
        return;
    }
    int w = t >> 6, l = t & 63, c = l & 15, G = l >> 4;
    int T = blockIdx.x * 4 + w;
    if (T >= 3125) return;           // no barriers in this kernel -> safe
    int n0 = T * 16;
    const bf16x8* Bp = (const bf16x8*)Bpack;

    const float* hp = h + (size_t)(n0 + c) * 128 + 8 * G;
    bf16x8 a[4];
    #pragma unroll
    for (int s = 0; s < 4; ++s) {
        float4 lo = *(const float4*)(hp + 32 * s);
        float4 hi = *(const float4*)(hp + 32 * s + 4);
        a[s][0] = (short)f2bf(lo.x); a[s][1] = (short)f2bf(lo.y);
        a[s][2] = (short)f2bf(lo.z); a[s][3] = (short)f2bf(lo.w);
        a[s][4] = (short)f2bf(hi.x); a[s][5] = (short)f2bf(hi.y);
        a[s][6] = (short)f2bf(hi.z); a[s][7] = (short)f2bf(hi.w);
    }
    f32x4 acc[4] = {{0.f,0.f,0.f,0.f},{0.f,0.f,0.f,0.f},{0.f,0.f,0.f,0.f},{0.f,0.f,0.f,0.f}};
    #pragma unroll
    for (int n = 0; n < 4; ++n)
        #pragma unroll
        for (int s = 0; s < 4; ++s)
            acc[n] = __builtin_amdgcn_mfma_f32_16x16x32_bf16(a[s], Bp[(10 + 4*s + n)*64 + l], acc[n], 0, 0, 0);

    float was[4], wad[4];
    #pragma unroll
    for (int n = 0; n < 4; ++n) { was[n] = Wa[16*n + c]; wad[n] = Wa[96 + 16*n + c]; }

    #pragma unroll
    for (int r = 0; r < 4; ++r) {
        int row = n0 + 4 * G + r;
        #pragma unroll
        for (int n = 0; n < 4; ++n) {
            z[(size_t)row * 64 + 16 * n + c] = acc[n][r];
            zl[w][(4 * G + r) * 68 + 16 * n + c] = acc[n][r];
        }
        float ps = acc[0][r]*was[0] + acc[1][r]*was[1] + acc[2][r]*was[2] + acc[3][r]*was[3];
        float pd = acc[0][r]*wad[0] + acc[1][r]*wad[1] + acc[2][r]*wad[2] + acc[3][r]*wad[3];
        ps += __shfl_xor(ps, 1); ps += __shfl_xor(ps, 2);
        ps += __shfl_xor(ps, 4); ps += __shfl_xor(ps, 8);
        pd += __shfl_xor(pd, 1); pd += __shfl_xor(pd, 2);
        pd += __shfl_xor(pd, 4); pd += __shfl_xor(pd, 8);
        if (c == 0) { asrc[row] = ps; adst[row] = pd; }
    }

    bf16x8 ay[2];
    #pragma unroll
    for (int s = 0; s < 2; ++s)
        #pragma unroll
        for (int j = 0; j < 8; ++j)
            ay[s][j] = (short)f2bf(zl[w][c * 68 + 32 * s + 8 * G + j]);
    f32x4 accy[4] = {{0.f,0.f,0.f,0.f},{0.f,0.f,0.f,0.f},{0.f,0.f,0.f,0.f},{0.f,0.f,0.f,0.f}};
    #pragma unroll
    for (int n = 0; n < 4; ++n)
        #pragma unroll
        for (int s = 0; s < 2; ++s)
            accy[n] = __builtin_amdgcn_mfma_f32_16x16x32_bf16(ay[s], Bp[(26 + 4*s + n)*64 + l], accy[n], 0, 0, 0);
    #pragma unroll
    for (int r = 0; r < 4; ++r) {
        ushort4 yo;
        yo.x = f2bf(accy[0][r]); yo.y = f2bf(accy[1][r]);
        yo.z = f2bf(accy[2][r]); yo.w = f2bf(accy[3][r]);
        y16p[(size_t)(n0 + 4 * G + r) * 16 + c] = yo;
    }
}

// ---- CSR scans ----
__global__ __launch_bounds__(256) void scan1_kernel(const int* __restrict__ degi,
                                                    int* __restrict__ partial) {
    int t = threadIdx.x, i = blockIdx.x * 256 + t;
    int d = (i < N_NODES) ? degi[i] : 0;
    #pragma unroll
    for (int off = 32; off; off >>= 1) d += __shfl_down(d, off);
    __shared__ int wsum[4];
    if ((t & 63) == 0) wsum[t >> 6] = d;
    __syncthreads();
    if (t == 0) partial[blockIdx.x] = wsum[0] + wsum[1] + wsum[2] + wsum[3];
}

__global__ __launch_bounds__(256) void scan2_kernel(int* __restrict__ partial) {
    __shared__ int s[256];
    int t = threadIdx.x;
    int v = (t < NB1) ? partial[t] : 0;
    s[t] = v; __syncthreads();
    for (int off = 1; off < 256; off <<= 1) {
        int x = (t >= off) ? s[t - off] : 0;
        __syncthreads();
        s[t] += x;
        __syncthreads();
    }
    if (t < NB1) partial[t] = s[t] - v;   // exclusive, in place
}

__global__ __launch_bounds__(256) void scan3_kernel(const int* __restrict__ degi,
                                                    const int* __restrict__ partial,
                                                    int* __restrict__ start) {
    __shared__ int s[256];
    int t = threadIdx.x, i = blockIdx.x * 256 + t;
    int d = (i < N_NODES) ? degi[i] : 0;
    s[t] = d; __syncthreads();
    for (int off = 1; off < 256; off <<= 1) {
        int x = (t >= off) ? s[t - off] : 0;
        __syncthreads();
        s[t] += x;
        __syncthreads();
    }
    if (i < N_NODES) start[i] = partial[blockIdx.x] + s[t] - d;
}

// ---- Edge pass: stream edge_feat; MFMA q = ef@Wc^T; u = q + y16p[src];
//      scatter bf16(u) to CSR slot as ONE FULL 128B line + 4B ex scatter. ----
__global__ __launch_bounds__(256, 2) void edge_kernel(
    const float* __restrict__ edge_feat, const int* __restrict__ src,
    const int* __restrict__ dst, const int* __restrict__ ranks,
    const int* __restrict__ start, const float* __restrict__ asrc,
    const float* __restrict__ adst, const short* __restrict__ Bpack,
    const ushort4* __restrict__ y16p,
    unsigned short* __restrict__ wout, float* __restrict__ exslot)
{
    int t = threadIdx.x, w = t >> 6, l = t & 63;
    int c = l & 15, G = l >> 4;
    int wbase = blockIdx.x * 256 + w * 64;   // grid exact: 3125*256 = 800000

    const bf16x8* Bp = (const bf16x8*)Bpack;
    bf16x8 bc[8];
    #pragma unroll
    for (int f = 0; f < 8; ++f) bc[f] = Bp[f * 64 + l];
    bf16x8 b2a = Bp[8 * 64 + l];
    bf16x8 b2b = Bp[9 * 64 + l];

    int e = wbase + l;
    int se = src[e];
    int de = dst[e];
    int slot = start[de] + ranks[e];
    float apre = asrc[se] + adst[de];

    const float* efr = edge_feat + (size_t)(wbase + c) * 64 + G * 8;
    float4 n0 = *(const float4*)(efr);
    float4 n1 = *(const float4*)(efr + 4);
    float4 n2 = *(const float4*)(efr + 32);
    float4 n3 = *(const float4*)(efr + 36);

    #pragma unroll
    for (int k = 0; k < 4; ++k) {
        float4 c0 = n0, c1 = n1, c2 = n2, c3 = n3;
        if (k < 3) {
            const float* efn = edge_feat + (size_t)(wbase + 16 * (k + 1) + c) * 64 + G * 8;
            n0 = *(const float4*)(efn);
            n1 = *(const float4*)(efn + 4);
            n2 = *(const float4*)(efn + 32);
            n3 = *(const float4*)(efn + 36);
        }
        // per-edge meta for this batch's 4 group-edges; issue y-gathers early
        int sr[4], sl4[4]; float ap[4];
        #pragma unroll
        for (int r = 0; r < 4; ++r) {
            int si = 16 * k + 4 * G + r;
            sr[r]  = __shfl(se, si);
            sl4[r] = __shfl(slot, si);
            ap[r]  = __shfl(apre, si);
        }
        ushort4 yv[4];
        #pragma unroll
        for (int r = 0; r < 4; ++r) yv[r] = y16p[(size_t)sr[r] * 16 + c];

        bf16x8 a0, a1;
        a0[0] = (short)f2bf(c0.x); a0[1] = (short)f2bf(c0.y);
        a0[2] = (short)f2bf(c0.z); a0[3] = (short)f2bf(c0.w);
        a0[4] = (short)f2bf(c1.x); a0[5] = (short)f2bf(c1.y);
        a0[6] = (short)f2bf(c1.z); a0[7] = (short)f2bf(c1.w);
        a1[0] = (short)f2bf(c2.x); a1[1] = (short)f2bf(c2.y);
        a1[2] = (short)f2bf(c2.z); a1[3] = (short)f2bf(c2.w);
        a1[4] = (short)f2bf(c3.x); a1[5] = (short)f2bf(c3.y);
        a1[6] = (short)f2bf(c3.z); a1[7] = (short)f2bf(c3.w);

        f32x4 acc[4] = {{0.f,0.f,0.f,0.f},{0.f,0.f,0.f,0.f},{0.f,0.f,0.f,0.f},{0.f,0.f,0.f,0.f}};
        f32x4 acc2 = {0.f, 0.f, 0.f, 0.f};
        #pragma unroll
        for (int n = 0; n < 4; ++n) {
            acc[n] = __builtin_amdgcn_mfma_f32_16x16x32_bf16(a0, bc[n], acc[n], 0, 0, 0);
            acc[n] = __builtin_amdgcn_mfma_f32_16x16x32_bf16(a1, bc[4 + n], acc[n], 0, 0, 0);
        }
        acc2 = __builtin_amdgcn_mfma_f32_16x16x32_bf16(a0, b2a, acc2, 0, 0, 0);
        acc2 = __builtin_amdgcn_mfma_f32_16x16x32_bf16(a1, b2b, acc2, 0, 0, 0);
        // acc[n][r] = q[edge 16k+4G+r][col 16n+c]; acc2[r] = p (col0 at c==0)

        #pragma unroll
        for (int r = 0; r < 4; ++r) {
            float u0 = acc[0][r] + bf2f(yv[r].x);
            float u1 = acc[1][r] + bf2f(yv[r].y);
            float u2 = acc[2][r] + bf2f(yv[r].z);
            float u3 = acc[3][r] + bf2f(yv[r].w);
            uint2 o;
            o.x = pack2bf(u0, u1);
            o.y = pack2bf(u2, u3);
            // full 128B line per slot, 16 lanes x 8B, no RMW
            *(uint2*)&wout[(size_t)sl4[r] * 64 + 4 * c] = o;
            if (c == 0) {
                float aa = ap[r] + acc2[r];
                float sg = aa > 0.f ? aa : 0.01f * aa;
                exslot[sl4[r]] = __expf(sg);   // segmax shift mathematically redundant
            }
        }
    }
}

// ---- Pass B: PURE STREAMING segmented sum. No gathers, no LDS, no shuffles.
//      lane l holds component 16*(l&3)+(l>>2); wout ushort index l == that comp. ----
__global__ __launch_bounds__(256) void agg_kernel(
    const unsigned short* __restrict__ wout, const float* __restrict__ exslot,
    const int* __restrict__ start, const int* __restrict__ degi,
    const float* __restrict__ z, float* __restrict__ out)
{
    int t = threadIdx.x, w = t >> 6, l = t & 63;
    int d    = blockIdx.x * 4 + w;           // grid exact: 12500*4 = 50000
    int base = __builtin_amdgcn_readfirstlane(start[d]);
    int deg  = __builtin_amdgcn_readfirstlane(degi[d]);
    const unsigned short* wp = wout + (size_t)base * 64 + l;
    const float* xp = exslot + base;

    float acc = 0.f, den = 0.f;
    for (int i = 0; i < deg; i += 8) {
        #pragma unroll
        for (int j = 0; j < 8; ++j) {
            int idx = i + j;
            bool vld = idx < deg;
            int ic = vld ? idx : deg - 1;      // clamped: always in-bounds
            unsigned short v = wp[(size_t)ic * 64];
            float x = vld ? xp[ic] : 0.f;
            acc += x * bf2f(v);
            den += x;
        }
    }

    int comp = 16 * (l & 3) + (l >> 2);
    if (deg > 0)
        out[(size_t)d * 64 + comp] = acc / den;
    else
        out[(size_t)d * 64 + comp] = z[(size_t)d * 64 + comp];
}

extern "C" void kernel_launch(void* const* d_in, const int* in_sizes, int n_in,
                              void* d_out, int out_size, void* d_ws, size_t ws_size,
                              hipStream_t stream) {
    const float* h         = (const float*)d_in[0];
    const float* edge_feat = (const float*)d_in[1];
    const int*   src       = (const int*)d_in[2];
    const int*   dst       = (const int*)d_in[3];
    const float* Wn        = (const float*)d_in[4];
    const float* We        = (const float*)d_in[5];
    const float* Wa        = (const float*)d_in[6];
    const float* W2        = (const float*)d_in[7];
    float* out = (float*)d_out;

    char* p = (char*)d_ws;
    // wout FIRST: keeps 128B line alignment for the full-line scatter
    unsigned short* wout   = (unsigned short*)p; p += (size_t)N_EDGES * 64 * 2;   // 102.4 MB
    float*          z      = (float*)p;          p += (size_t)N_NODES * 64 * 4;   // 12.8 MB
    ushort4*        y16p   = (ushort4*)p;        p += (size_t)N_NODES * 64 * 2;   // 6.4 MB
    float*          exslot = (float*)p;          p += (size_t)N_EDGES * 4;        // 3.2 MB
    float*          asrc   = (float*)p;          p += (size_t)N_NODES * 4;
    float*          adst   = (float*)p;          p += (size_t)N_NODES * 4;
    int*            degi   = (int*)p;            p += (size_t)N_NODES * 4;
    int*            start  = (int*)p;            p += (size_t)N_NODES * 4;
    int*            ranks  = (int*)p;            p += (size_t)N_EDGES * 4;        // 3.2 MB
    int*            partial= (int*)p;            p += (size_t)256 * 4;
    short*          Bpack  = (short*)p;          p += (size_t)34 * 512 * 2;       // 35 KB

    kw_kernel<<<NB1, 256, 0, stream>>>(We, Wa, Wn, W2, Bpack, degi);
    node_hist_kernel<<<782 + 3125, 256, 0, stream>>>(h, Wa, Bpack, dst, z, y16p,
                                                     asrc, adst, degi, ranks);
    scan1_kernel<<<NB1, 256, 0, stream>>>(degi, partial);
    scan2_kernel<<<1, 256, 0, stream>>>(partial);
    scan3_kernel<<<NB1, 256, 0, stream>>>(degi, partial, start);
    edge_kernel<<<3125, 256, 0, stream>>>(edge_feat, src, dst, ranks, start,
                                          asrc, adst, Bpack, y16p, wout, exslot);
    agg_kernel<<<N_NODES / 4, 256, 0, stream>>>(wout, exslot, start, degi, z, out);
}